// Round 8
// baseline (184.319 us; speedup 1.0000x reference)
//
#include <hip/hip_runtime.h>
#include <hip/hip_bf16.h>

typedef short bf16x8 __attribute__((ext_vector_type(8)));
typedef short bf16x4 __attribute__((ext_vector_type(4)));
typedef float f32x4  __attribute__((ext_vector_type(4)));

#define NI 256
#define NJ 256
#define NC 128
#define NH 4
#define ND 32

// ---- workspace layout (bytes) ----
#define WB_OFF    0           // wq|wk|wv|wo bf16 [512][128] linear
#define XN_OFF    131072      // xn bf16 [65536 tok][128]
#define TBM_OFF   16908288    // [256 i][4 h][256 j] f32 (tb + mask bias)

// sigma(t) = ((t&15)>>2)*8 + (t&3) + (t>>4)*4  — inverse of the pack8 k-slot perm pi

__device__ __forceinline__ short f2bf(float f) {
    return __builtin_bit_cast(short, __float2bfloat16(f));
}
__device__ __forceinline__ bf16x8 pack8(f32x4 lo, f32x4 hi) {
    bf16x8 u;
    #pragma unroll
    for (int j = 0; j < 4; ++j) { u[j] = f2bf(lo[j]); u[4 + j] = f2bf(hi[j]); }
    return u;
}

// ================= k_pre: LN + tb + mask bias (blocks 0..1023); weight conv (1024..1055) =================
__global__ __launch_bounds__(256, 8)
void k_pre(const float* __restrict__ x, const float* __restrict__ mask,
           const float* __restrict__ ln_g, const float* __restrict__ ln_b,
           const float* __restrict__ wb, const float* __restrict__ wq,
           const float* __restrict__ wk, const float* __restrict__ wv,
           const float* __restrict__ wo, char* __restrict__ ws)
{
    const int bid = blockIdx.x;
    const int tid = threadIdx.x;

    if (bid >= 1024) {   // ---- weights -> bf16, all linear ----
        const int base = ((bid - 1024) * 256 + tid) * 8;   // 65536 elems
        const float* arr[4] = {wq, wk, wv, wo};
        const float* src = arr[base >> 14] + (base & 16383);
        short* dst = (short*)(ws + WB_OFF) + base;
        #pragma unroll
        for (int u = 0; u < 2; ++u) {
            f32x4 v = *(const f32x4*)(src + 4 * u);
            bf16x4 o;
            #pragma unroll
            for (int r = 0; r < 4; ++r) o[r] = f2bf(v[r]);
            *(bf16x4*)(dst + 4 * u) = o;
        }
        return;
    }

    // ---- LN: lane-linear loads; lanes 0-31 = token 2k, 32-63 = token 2k+1 ----
    const int lane = tid & 63;
    const int wv_  = tid >> 6;
    const int l5   = lane & 31;
    const int half = lane >> 5;
    const int c0   = l5 * 4;

    f32x4 gv = *(const f32x4*)(ln_g + c0);
    f32x4 bv = *(const f32x4*)(ln_b + c0);
    f32x4 gwv[4];
    float Gh[4], Bh[4];
    #pragma unroll
    for (int h = 0; h < 4; ++h) {
        f32x4 w = *(const f32x4*)(wb + h * NC + c0);
        #pragma unroll
        for (int e = 0; e < 4; ++e) gwv[h][e] = gv[e] * w[e];
        Gh[h] = (gwv[h][0] + gwv[h][1]) + (gwv[h][2] + gwv[h][3]);
        Bh[h] = (bv[0] * w[0] + bv[1] * w[1]) + (bv[2] * w[2] + bv[3] * w[3]);
    }
    #pragma unroll
    for (int dd = 1; dd < 32; dd <<= 1) {
        #pragma unroll
        for (int h = 0; h < 4; ++h) {
            Gh[h] += __shfl_xor(Gh[h], dd);
            Bh[h] += __shfl_xor(Bh[h], dd);
        }
    }

    short* xnb = (short*)(ws + XN_OFF);
    float* tbm = (float*)(ws + TBM_OFF);
    const int t0 = bid * 64 + wv_ * 16;

    #pragma unroll
    for (int it = 0; it < 2; ++it) {
        const int tb8 = t0 + it * 8;
        const float* bp = x + (size_t)tb8 * NC;
        #pragma unroll
        for (int k = 0; k < 4; ++k) {
            f32x4 v = *(const f32x4*)(bp + k * 256 + lane * 4);   // lane-linear 16B
            const int tk = tb8 + k * 2 + half;
            float s  = v[0] + v[1] + v[2] + v[3];
            float s2 = v[0]*v[0] + v[1]*v[1] + v[2]*v[2] + v[3]*v[3];
            float d0 = v[0]*gwv[0][0] + v[1]*gwv[0][1] + v[2]*gwv[0][2] + v[3]*gwv[0][3];
            float d1 = v[0]*gwv[1][0] + v[1]*gwv[1][1] + v[2]*gwv[1][2] + v[3]*gwv[1][3];
            float d2 = v[0]*gwv[2][0] + v[1]*gwv[2][1] + v[2]*gwv[2][2] + v[3]*gwv[2][3];
            float d3 = v[0]*gwv[3][0] + v[1]*gwv[3][1] + v[2]*gwv[3][2] + v[3]*gwv[3][3];
            #pragma unroll
            for (int dd = 1; dd < 32; dd <<= 1) {
                s  += __shfl_xor(s, dd);
                s2 += __shfl_xor(s2, dd);
                d0 += __shfl_xor(d0, dd);
                d1 += __shfl_xor(d1, dd);
                d2 += __shfl_xor(d2, dd);
                d3 += __shfl_xor(d3, dd);
            }
            const float mu  = s * 0.0078125f;
            const float var = s2 * 0.0078125f - mu * mu;
            const float rs  = rsqrtf(var + 1e-5f);
            bf16x4 o;
            #pragma unroll
            for (int e = 0; e < 4; ++e) o[e] = f2bf((v[e] - mu) * rs * gv[e] + bv[e]);
            *(bf16x4*)(xnb + (size_t)tk * NC + c0) = o;
            if (l5 == 0) {
                const float mb = 1.0e9f * (mask[tk] - 1.0f);
                const int ii = tk >> 8, jj = tk & 255;
                const float d4[4] = {d0, d1, d2, d3};
                #pragma unroll
                for (int h = 0; h < 4; ++h)
                    tbm[(size_t)(ii * NH + h) * NJ + jj] = rs * (d4[h] - mu * Gh[h]) + Bh[h] + mb;
            }
        }
    }
}

// ================= k_fat4: per-row-i, 4-head LDS K/V, barrier-free attention =================
// LDS: kb[h] = [256][40] at h*20480 (81,920 B); vb[h] = [32][264] at 81920+h*16896 (67,584 B).
// After barrier 2, kb region is reused as ol[256][136] bf16 (69,632 B).
#define SMEM_FAT 149504
__global__ __launch_bounds__(1024, 4)
void k_fat4(const char* __restrict__ ws, const float* __restrict__ wo_b,
            float* __restrict__ out)
{
    extern __shared__ __align__(16) char smem[];
    const int tid  = threadIdx.x;
    const int lane = tid & 63;
    const int wid  = tid >> 6;          // 0..15
    const int g    = lane >> 4;
    const int l16  = lane & 15;
    const int i    = blockIdx.x;        // grid 256
    const int t0   = wid * 16;          // phase A/C token range

    const short* xn   = (const short*)(ws + XN_OFF) + (size_t)i * NJ * NC;
    const short* wqkv = (const short*)(ws + WB_OFF);
    const short* wob  = (const short*)(ws + WB_OFF) + 49152;
    const float* tbm  = (const float*)(ws + TBM_OFF) + (size_t)i * NH * NJ;

    const f32x4 z4 = {0.f, 0.f, 0.f, 0.f};
    const float SCALE = 0.17677669529663687f;  // 1/sqrt(32)

    // ---- Phase A: wave projects K,V of its 16 tokens for ALL 4 heads (xn read once) ----
    {
        bf16x8 af[4];
        #pragma unroll
        for (int ks = 0; ks < 4; ++ks)
            af[ks] = *(const bf16x8*)(xn + (size_t)(t0 + l16) * NC + ks * 32 + g * 8);
        #pragma unroll
        for (int h = 0; h < 4; ++h) {
            short (*kb)[40]  = (short(*)[40]) (smem + h * 20480);
            short (*vb)[264] = (short(*)[264])(smem + 81920 + h * 16896);
            #pragma unroll
            for (int sub = 0; sub < 2; ++sub) {   // K -> kb[tok][sigma(d)]
                f32x4 acc = z4;
                #pragma unroll
                for (int ks = 0; ks < 4; ++ks) {
                    bf16x8 w = *(const bf16x8*)(wqkv + (size_t)(NC + h * ND + sub * 16 + l16) * NC + ks * 32 + g * 8);
                    acc = __builtin_amdgcn_mfma_f32_16x16x32_bf16(af[ks], w, acc, 0, 0, 0);
                }
                const int col = ((l16 >> 2) << 3) + (l16 & 3) + (sub << 2);   // sigma
                #pragma unroll
                for (int r = 0; r < 4; ++r)
                    kb[t0 + g * 4 + r][col] = f2bf(acc[r]);
            }
            #pragma unroll
            for (int sub = 0; sub < 2; ++sub) {   // V -> vb[d][sigma-permuted token]
                f32x4 acc = z4;
                #pragma unroll
                for (int ks = 0; ks < 4; ++ks) {
                    bf16x8 w = *(const bf16x8*)(wqkv + (size_t)(2 * NC + h * ND + sub * 16 + l16) * NC + ks * 32 + g * 8);
                    acc = __builtin_amdgcn_mfma_f32_16x16x32_bf16(af[ks], w, acc, 0, 0, 0);
                }
                bf16x4 pk;
                #pragma unroll
                for (int r = 0; r < 4; ++r) pk[r] = f2bf(acc[r]);
                *(bf16x4*)(&vb[sub * 16 + l16][((t0 >> 5) << 5) + (g << 3) + (((t0 >> 4) & 1) << 2)]) = pk;
            }
        }
    }
    __syncthreads();   // barrier 1: K/V ready

    // ---- Phase B (no barriers): wave owns head h = wid>>2, queries qb..qb+63 ----
    const int h  = wid >> 2;            // 4 distinct heads per SIMD
    const int qb = (wid & 3) * 64;
    const short (*kb)[40]  = (const short(*)[40]) (smem + h * 20480);
    const short (*vb)[264] = (const short(*)[264])(smem + 81920 + h * 16896);

    bf16x4 keep[4][2];   // normalized O (bf16) per q-tile
    #pragma unroll
    for (int qt = 0; qt < 4; ++qt) {
        const int q0 = qb + qt * 16;
        // q built in-register (swapped): D[d][q] -> pack8 -> B-frag
        bf16x8 aq[4];
        #pragma unroll
        for (int ks = 0; ks < 4; ++ks)
            aq[ks] = *(const bf16x8*)(xn + (size_t)(q0 + l16) * NC + ks * 32 + g * 8);
        f32x4 a0 = z4, a1 = z4;
        #pragma unroll
        for (int ks = 0; ks < 4; ++ks) {
            bf16x8 w0 = *(const bf16x8*)(wqkv + (size_t)(h * ND + l16) * NC + ks * 32 + g * 8);
            bf16x8 w1 = *(const bf16x8*)(wqkv + (size_t)(h * ND + 16 + l16) * NC + ks * 32 + g * 8);
            a0 = __builtin_amdgcn_mfma_f32_16x16x32_bf16(w0, aq[ks], a0, 0, 0, 0);
            a1 = __builtin_amdgcn_mfma_f32_16x16x32_bf16(w1, aq[ks], a1, 0, 0, 0);
        }
        bf16x8 qf = pack8(a0, a1);
        const float tbq = tbm[h * NJ + q0 + l16];

        // QK^T swapped: lane owns query q0+l16; 64 scores in s[16]
        f32x4 s[16];
        #pragma unroll
        for (int kt = 0; kt < 16; ++kt) {
            bf16x8 kf = *(const bf16x8*)(&kb[kt * 16 + l16][g * 8]);
            s[kt] = __builtin_amdgcn_mfma_f32_16x16x32_bf16(kf, qf, z4, 0, 0, 0);
        }
        #pragma unroll
        for (int kt = 0; kt < 16; ++kt)
            #pragma unroll
            for (int r = 0; r < 4; ++r)
                s[kt][r] = fmaf(s[kt][r], SCALE, tbq);  // fp32: masked rows collapse exactly

        float mk[16];
        #pragma unroll
        for (int kt = 0; kt < 16; ++kt)
            mk[kt] = fmaxf(fmaxf(s[kt][0], s[kt][1]), fmaxf(s[kt][2], s[kt][3]));
        #pragma unroll
        for (int st = 8; st >= 1; st >>= 1)
            #pragma unroll
            for (int k2 = 0; k2 < st; ++k2) mk[k2] = fmaxf(mk[k2], mk[k2 + st]);
        float m = mk[0];
        m = fmaxf(m, __shfl_xor(m, 16));
        m = fmaxf(m, __shfl_xor(m, 32));

        float sk[16];
        #pragma unroll
        for (int kt = 0; kt < 16; ++kt) {
            #pragma unroll
            for (int r = 0; r < 4; ++r) s[kt][r] = __expf(s[kt][r] - m);
            sk[kt] = (s[kt][0] + s[kt][1]) + (s[kt][2] + s[kt][3]);
        }
        #pragma unroll
        for (int st = 8; st >= 1; st >>= 1)
            #pragma unroll
            for (int k2 = 0; k2 < st; ++k2) sk[k2] += sk[k2 + st];
        float sum = sk[0];
        sum += __shfl_xor(sum, 16);
        sum += __shfl_xor(sum, 32);
        const float inv = 1.0f / sum;

        // PV: P packed in-register; V^T from sigma-permuted LDS
        f32x4 o0 = z4, o1 = z4;
        #pragma unroll
        for (int c = 0; c < 8; ++c) {
            bf16x8 pa = pack8(s[2 * c], s[2 * c + 1]);
            bf16x8 v0 = *(const bf16x8*)(&vb[l16][c * 32 + g * 8]);
            bf16x8 v1 = *(const bf16x8*)(&vb[16 + l16][c * 32 + g * 8]);
            o0 = __builtin_amdgcn_mfma_f32_16x16x32_bf16(v0, pa, o0, 0, 0, 0);
            o1 = __builtin_amdgcn_mfma_f32_16x16x32_bf16(v1, pa, o1, 0, 0, 0);
        }
        bf16x4 p0, p1;
        #pragma unroll
        for (int r = 0; r < 4; ++r) { p0[r] = f2bf(o0[r] * inv); p1[r] = f2bf(o1[r] * inv); }
        keep[qt][0] = p0;
        keep[qt][1] = p1;
    }
    __syncthreads();   // barrier 2: all K/V reads done -> kb region reusable

    // ---- O -> LDS overlay (plain d order): ol[q][h*32 + d] ----
    short (*ol)[136] = (short(*)[136])(smem);
    #pragma unroll
    for (int qt = 0; qt < 4; ++qt) {
        const int q = qb + qt * 16 + l16;   // D col = q on l16
        *(bf16x4*)(&ol[q][h * ND + g * 4])      = keep[qt][0];   // rows d = g*4+r
        *(bf16x4*)(&ol[q][h * ND + 16 + g * 4]) = keep[qt][1];
    }
    __syncthreads();   // barrier 3: O complete

    // ---- out-projection: D cols = out channels -> 64B-sector coalesced stores ----
    bf16x8 oaf[4];
    #pragma unroll
    for (int ks = 0; ks < 4; ++ks)
        oaf[ks] = *(const bf16x8*)(&ol[t0 + l16][ks * 32 + g * 8]);
    #pragma unroll
    for (int ct = 0; ct < 8; ++ct) {
        bf16x8 bfr[4];
        #pragma unroll
        for (int ks = 0; ks < 4; ++ks)
            bfr[ks] = *(const bf16x8*)(wob + (size_t)(ct * 16 + l16) * NC + ks * 32 + g * 8);
        f32x4 acc = z4;
        #pragma unroll
        for (int ks = 0; ks < 4; ++ks)
            acc = __builtin_amdgcn_mfma_f32_16x16x32_bf16(oaf[ks], bfr[ks], acc, 0, 0, 0);
        const float bias = wo_b[ct * 16 + l16];
        #pragma unroll
        for (int r = 0; r < 4; ++r)
            out[((size_t)i * NJ + t0 + g * 4 + r) * NC + ct * 16 + l16] = acc[r] + bias;
    }
}

extern "C" void kernel_launch(void* const* d_in, const int* in_sizes, int n_in,
                              void* d_out, int out_size, void* d_ws, size_t ws_size,
                              hipStream_t stream) {
    const float* x    = (const float*)d_in[0];
    const float* mask = (const float*)d_in[1];
    const float* ln_g = (const float*)d_in[2];
    const float* ln_b = (const float*)d_in[3];
    const float* wq   = (const float*)d_in[4];
    const float* wk   = (const float*)d_in[5];
    const float* wv   = (const float*)d_in[6];
    const float* wb   = (const float*)d_in[7];
    const float* wo   = (const float*)d_in[8];
    const float* wo_b = (const float*)d_in[9];
    float* out = (float*)d_out;
    char* ws   = (char*)d_ws;

    (void)hipFuncSetAttribute((const void*)k_fat4,
                              hipFuncAttributeMaxDynamicSharedMemorySize, SMEM_FAT);

    k_pre <<<dim3(1056), dim3(256),  0,        stream>>>(x, mask, ln_g, ln_b, wb, wq, wk, wv, wo, ws);
    k_fat4<<<dim3(NI),   dim3(1024), SMEM_FAT, stream>>>(ws, wo_b, out);
}